// Round 2
// baseline (179.733 us; speedup 1.0000x reference)
//
#include <hip/hip_runtime.h>

#define BB 4096
#define TT 512
#define KK 7
#define SS 16
#define NMAT (BB * 31 * 7)   // matrix-row threads: (b, chunk 1..31, row i)

__device__ __forceinline__ float fexp2(float x){ float r; asm("v_exp_f32 %0, %1" : "=v"(r) : "v"(x)); return r; }
__device__ __forceinline__ float flog2(float x){ float r; asm("v_log_f32 %0, %1" : "=v"(r) : "v"(x)); return r; }
// force wave-uniform value into SGPR (e2 table is identical for all threads)
__device__ __forceinline__ float uni(float x){ return __int_as_float(__builtin_amdgcn_readfirstlane(__float_as_int(x))); }

// Phase 1: row-split chunk scan.
//  tid < NMAT:   thread = (b, c in 1..31, i) -> row i of chunk-c 7x7 log-map
//  tid >= NMAT:  thread = b -> alpha vector over chunk 0 (t=0..15)
__global__ __launch_bounds__(256) void crf_p1(
    const float* __restrict__ em, const int* __restrict__ msk,
    const float* __restrict__ trn, const float* __restrict__ stt,
    float* __restrict__ wsA, float* __restrict__ wsP)
{
  const float L2E = 1.44269504088896340736f;
  int tid = blockIdx.x * 256 + threadIdx.x;

  // exp2(transitions) -- wave-uniform, lives in SGPRs
  float e2[49];
  #pragma unroll
  for (int i = 0; i < 49; i++) e2[i] = uni(fexp2(trn[i] * L2E));

  if (tid < NMAT) {
    // ---------- matrix-row chunk ----------
    int q = tid / 7, i = tid - q * 7;
    int b = q / 31, c = q - b * 31 + 1;
    int t0 = c * SS;
    const size_t eb = (size_t)b * (TT * KK);

    float R[KK];
    #pragma unroll
    for (int j = 0; j < KK; j++) R[j] = (j == i) ? 1.f : 0.f;
    float Lr = 0.f; int cnt = 0; int alive = 1;

    for (int g = 0; g < 4; g++) {
      if (!alive) break;
      int t = t0 + 4 * g;
      float em_[28];
      #pragma unroll
      for (int p = 0; p < 7; p++) {
        float4 f = *(const float4*)(em + eb + (size_t)t * KK + 4 * p);
        em_[4*p+0] = f.x; em_[4*p+1] = f.y; em_[4*p+2] = f.z; em_[4*p+3] = f.w;
      }
      int4 m4 = *(const int4*)(msk + b * TT + t);
      int ms[4] = {m4.x, m4.y, m4.z, m4.w};
      #pragma unroll
      for (int s = 0; s < 4; s++) {
        if (!ms[s]) { alive = 0; break; }
        cnt++;
        float acc[KK];
        #pragma unroll
        for (int j = 0; j < KK; j++) acc[j] = R[0] * e2[j];
        #pragma unroll
        for (int k = 1; k < KK; k++)
          #pragma unroll
          for (int j = 0; j < KK; j++) acc[j] = fmaf(R[k], e2[k*KK + j], acc[j]);
        #pragma unroll
        for (int j = 0; j < KK; j++) R[j] = acc[j] * fexp2(em_[s*KK + j] * L2E);
        if ((cnt & 3) == 0) {       // exact pow2 renorm (same cadence as before)
          float mm = R[0];
          #pragma unroll
          for (int j = 1; j < KK; j++) mm = fmaxf(mm, R[j]);
          int ex = (int)((__float_as_uint(mm) >> 23) & 255) - 127;
          float scl = __uint_as_float((unsigned)(127 - ex) << 23);
          Lr += (float)ex;
          #pragma unroll
          for (int j = 0; j < KK; j++) R[j] *= scl;
        }
      }
    }
    if (cnt > 0) {
      float* P = wsP + ((size_t)(c - 1) * BB + b) * 49 + i * KK;
      #pragma unroll
      for (int j = 0; j < KK; j++) P[j] = Lr + flog2(R[j]);
    }
  } else {
    // ---------- alpha chunk (t = 0..15) ----------
    int b = tid - NMAT;
    const size_t eb = (size_t)b * (TT * KK);
    float em_[28];
    #pragma unroll
    for (int p = 0; p < 7; p++) {
      float4 f = *(const float4*)(em + eb + 4 * p);
      em_[4*p+0] = f.x; em_[4*p+1] = f.y; em_[4*p+2] = f.z; em_[4*p+3] = f.w;
    }
    int4 m4 = *(const int4*)(msk + b * TT);
    int ms[4] = {m4.x, m4.y, m4.z, m4.w};

    float u[KK], Ls;
    {
      float a2[KK];
      #pragma unroll
      for (int j = 0; j < KK; j++) a2[j] = (stt[j] + em_[j]) * L2E;
      float m = a2[0];
      #pragma unroll
      for (int j = 1; j < KK; j++) m = fmaxf(m, a2[j]);
      #pragma unroll
      for (int j = 0; j < KK; j++) u[j] = fexp2(a2[j] - m);
      Ls = m;
    }
    int cnt = ms[0]; int alive = 1;

    for (int g = 0; g < 4; g++) {
      if (g > 0) {
        if (!alive) break;
        int t = 4 * g;
        #pragma unroll
        for (int p = 0; p < 7; p++) {
          float4 f = *(const float4*)(em + eb + (size_t)t * KK + 4 * p);
          em_[4*p+0] = f.x; em_[4*p+1] = f.y; em_[4*p+2] = f.z; em_[4*p+3] = f.w;
        }
        int4 n4 = *(const int4*)(msk + b * TT + t);
        ms[0] = n4.x; ms[1] = n4.y; ms[2] = n4.z; ms[3] = n4.w;
      }
      #pragma unroll
      for (int s = 0; s < 4; s++) {
        if (g == 0 && s == 0) continue;   // t=0 was the init
        if (!ms[s]) { alive = 0; break; }
        cnt++;
        float acc[KK];
        #pragma unroll
        for (int j = 0; j < KK; j++) acc[j] = u[0] * e2[j];
        #pragma unroll
        for (int k = 1; k < KK; k++)
          #pragma unroll
          for (int j = 0; j < KK; j++) acc[j] = fmaf(u[k], e2[k*KK + j], acc[j]);
        #pragma unroll
        for (int j = 0; j < KK; j++) u[j] = acc[j] * fexp2(em_[s*KK + j] * L2E);
        if ((cnt & 3) == 0) {
          float mm = u[0];
          #pragma unroll
          for (int j = 1; j < KK; j++) mm = fmaxf(mm, u[j]);
          int ex = (int)((__float_as_uint(mm) >> 23) & 255) - 127;
          float scl = __uint_as_float((unsigned)(127 - ex) << 23);
          Ls += (float)ex;
          #pragma unroll
          for (int j = 0; j < KK; j++) u[j] *= scl;
        }
      }
    }
    #pragma unroll
    for (int j = 0; j < KK; j++) wsA[b * 8 + j] = Ls + flog2(u[j]);
  }
}

// Phase 2: one wave per b.  len from mask; tag-path score t-parallel across lanes;
// chunk combine with depth-2 prefetch; logZ; mean-reduce.
__global__ __launch_bounds__(256) void crf_p2(
    const float* __restrict__ em, const int* __restrict__ msk,
    const int* __restrict__ tgs, const float* __restrict__ trn,
    const float* __restrict__ stt, const float* __restrict__ ent,
    const float* __restrict__ wsA, const float* __restrict__ wsP,
    float* __restrict__ out)
{
  const float L2E = 1.44269504088896340736f;
  const float LN2 = 0.69314718055994530942f;
  __shared__ float sm[4];
  int w = threadIdx.x >> 6, lane = threadIdx.x & 63;
  int b = blockIdx.x * 4 + w;
  const int* mrow = msk + b * TT;
  const int* trow = tgs + b * TT;
  const size_t eb = (size_t)b * (TT * KK);

  // ---- sequence length from mask (prefix mask) ----
  int4 ma = *(const int4*)(mrow + lane * 8);
  int4 mb = *(const int4*)(mrow + lane * 8 + 4);
  int len = ma.x + ma.y + ma.z + ma.w + mb.x + mb.y + mb.z + mb.w;
  #pragma unroll
  for (int o = 1; o < 64; o <<= 1) len += __shfl_xor(len, o);

  // ---- tag-path score, t-parallel (lane l owns t = l*8 .. l*8+7) ----
  int4 ta = *(const int4*)(trow + lane * 8);
  int4 tb = *(const int4*)(trow + lane * 8 + 4);
  int tga[8] = {ta.x, ta.y, ta.z, ta.w, tb.x, tb.y, tb.z, tb.w};
  int tprev = lane ? trow[lane * 8 - 1] : 0;
  float scp = 0.f;
  #pragma unroll
  for (int s = 0; s < 8; s++) {
    int t = lane * 8 + s; int tg = tga[s];
    if (t == 0)          scp += stt[tg] + em[eb + tg];
    else if (t < len)    scp += trn[tprev * KK + tg] + em[eb + (size_t)t * KK + tg];
    if (t == len - 1)    scp += ent[tg];
    tprev = tg;
  }
  float score = scp;
  #pragma unroll
  for (int o = 1; o < 64; o <<= 1) score += __shfl_xor(score, o);

  // ---- combine chunk maps (lane j owns state j; depth-2 prefetch) ----
  float A = (lane < KK) ? wsA[b * 8 + lane] : -1e30f;
  int j = (lane < KK) ? lane : 0;
  int nact = (len - 1) >> 4; if (nact > 31) nact = 31;   // matrix chunks with >=1 active step
  const float* Pb = wsP + (size_t)b * 49;
  const size_t cs = (size_t)BB * 49;
  float cur[KK];
  if (nact >= 1) {
    #pragma unroll
    for (int i = 0; i < KK; i++) cur[i] = Pb[i * KK + j];
  }
  for (int c2 = 1; c2 <= nact; c2++) {
    float nxt[KK];
    if (c2 < nact) {
      #pragma unroll
      for (int i = 0; i < KK; i++) nxt[i] = Pb[(size_t)c2 * cs + i * KK + j];
    }
    float v[KK];
    #pragma unroll
    for (int i = 0; i < KK; i++) v[i] = __shfl(A, i) + cur[i];
    float m = v[0];
    #pragma unroll
    for (int i = 1; i < KK; i++) m = fmaxf(m, v[i]);
    float ssum = 0.f;
    #pragma unroll
    for (int i = 0; i < KK; i++) ssum += fexp2(v[i] - m);
    A = m + flog2(ssum);
    #pragma unroll
    for (int i = 0; i < KK; i++) cur[i] = nxt[i];
  }

  // ---- logZ and NLL ----
  float x = (lane < KK) ? A + ent[lane] * L2E : -1e30f;
  float mx = x;
  #pragma unroll
  for (int o = 1; o < 8; o <<= 1) mx = fmaxf(mx, __shfl_xor(mx, o));
  float se = fexp2(x - mx);
  #pragma unroll
  for (int o = 1; o < 8; o <<= 1) se += __shfl_xor(se, o);

  if (lane == 0) {
    float logz = LN2 * (mx + flog2(se));
    sm[w] = (logz - score) * (1.0f / BB);
  }
  __syncthreads();
  if (threadIdx.x == 0) atomicAdd(out, sm[0] + sm[1] + sm[2] + sm[3]);
}

extern "C" void kernel_launch(void* const* d_in, const int* in_sizes, int n_in,
                              void* d_out, int out_size, void* d_ws, size_t ws_size,
                              hipStream_t stream) {
  const float* em  = (const float*)d_in[0];
  const int*   msk = (const int*)d_in[1];
  const int*   tgs = (const int*)d_in[2];
  const float* trn = (const float*)d_in[3];
  const float* stt = (const float*)d_in[4];
  const float* ent = (const float*)d_in[5];
  float* out = (float*)d_out;

  float* wsA = (float*)d_ws;                 // BB*8 floats
  float* wsP = wsA + (size_t)BB * 8;         // 31*BB*49 floats

  hipMemsetAsync(out, 0, sizeof(float), stream);
  hipLaunchKernelGGL(crf_p1, dim3((NMAT + BB) / 256), dim3(256), 0, stream,
                     em, msk, trn, stt, wsA, wsP);
  hipLaunchKernelGGL(crf_p2, dim3(BB / 4), dim3(256), 0, stream,
                     em, msk, tgs, trn, stt, ent, wsA, wsP, out);
}

// Round 6
// 167.441 us; speedup vs baseline: 1.0734x; 1.0734x over previous
//
#include <hip/hip_runtime.h>

#define BB 4096
#define TT 512
#define KK 7
#define SS 16
#define NMAT (BB * 31 * 7)

__device__ __forceinline__ float fexp2(float x){ float r; asm("v_exp_f32 %0, %1" : "=v"(r) : "v"(x)); return r; }
__device__ __forceinline__ float flog2(float x){ float r; asm("v_log_f32 %0, %1" : "=v"(r) : "v"(x)); return r; }
__device__ __forceinline__ float uni(float x){ return __int_as_float(__builtin_amdgcn_readfirstlane(__float_as_int(x))); }

// ---------- p0: len[b] from prefix mask; also e2 table ----------
__global__ __launch_bounds__(256) void crf_len(
    const int* __restrict__ msk, const float* __restrict__ trn,
    int* __restrict__ wlen, float* __restrict__ wse2)
{
  const float L2E = 1.44269504088896340736f;
  if (blockIdx.x == 0 && threadIdx.x < 49)
    wse2[threadIdx.x] = fexp2(trn[threadIdx.x] * L2E);
  int gid = blockIdx.x * 256 + threadIdx.x;
  int b = gid >> 6, lane = gid & 63;
  int4 a = *(const int4*)(msk + b * TT + lane * 8);
  int4 c = *(const int4*)(msk + b * TT + lane * 8 + 4);
  int s = a.x + a.y + a.z + a.w + c.x + c.y + c.z + c.w;
  #pragma unroll
  for (int o = 1; o < 64; o <<= 1) s += __shfl_xor(s, o);
  if (lane == 0) wlen[b] = s;
}

__device__ __forceinline__ void loadg(float* B, const float* ep, int g){
  #pragma unroll
  for (int p = 0; p < 7; p++){
    float4 f = *(const float4*)(ep + g * 28 + 4 * p);
    B[4*p] = f.x; B[4*p+1] = f.y; B[4*p+2] = f.z; B[4*p+3] = f.w;
  }
}

// 4 steps of the row recurrence R' = (R @ E2) * 2^em, guarded by active count a.
template<int S0>
__device__ __forceinline__ void step4(float* R, float& Lr, const float* E,
                                      int base, int a, const float* e2){
  const float L2E = 1.44269504088896340736f;
  #pragma unroll
  for (int s = S0; s < 4; s++){
    if (base + s < a){
      float acc[KK];
      #pragma unroll
      for (int j = 0; j < KK; j++) acc[j] = R[0] * e2[j];
      #pragma unroll
      for (int k = 1; k < KK; k++)
        #pragma unroll
        for (int j = 0; j < KK; j++) acc[j] = fmaf(R[k], e2[k*KK + j], acc[j]);
      #pragma unroll
      for (int j = 0; j < KK; j++) R[j] = acc[j] * fexp2(E[s*KK + j] * L2E);
    }
  }
  if (base + 3 < a){                 // completed 4 steps -> exact pow2 renorm
    float mm = R[0];
    #pragma unroll
    for (int j = 1; j < KK; j++) mm = fmaxf(mm, R[j]);
    int ex = (int)((__float_as_uint(mm) >> 23) & 255) - 127;
    float scl = __uint_as_float((unsigned)(127 - ex) << 23);
    Lr += (float)ex;
    #pragma unroll
    for (int j = 0; j < KK; j++) R[j] *= scl;
  }
}

// ---------- p1: tid<NMAT -> (c,b,i) matrix row; else alpha vector ----------
__global__ __launch_bounds__(256) void crf_p1(
    const float* __restrict__ em, const int* __restrict__ wlen,
    const float* __restrict__ wse2, const float* __restrict__ stt,
    float* __restrict__ wsA, float* __restrict__ wsP)
{
  const float L2E = 1.44269504088896340736f;
  int tid = blockIdx.x * 256 + threadIdx.x;

  float e2[49];
  #pragma unroll
  for (int i = 0; i < 49; i++) e2[i] = uni(wse2[i]);

  if (tid < NMAT) {
    int q = tid / 7, i = tid - q * 7;
    int c = (q >> 12) + 1, b = q & (BB - 1);
    int t0 = c * SS;
    int len = wlen[b];
    int a = len - t0; a = a > 16 ? 16 : a;
    if (a > 0) {
      const float* ep = em + (size_t)b * (TT * KK) + (size_t)t0 * KK;
      float R[KK];
      #pragma unroll
      for (int j = 0; j < KK; j++) R[j] = (j == i) ? 1.f : 0.f;
      float Lr = 0.f;
      float bufA[28], bufB[28];
      loadg(bufA, ep, 0);
      if (a > 4) loadg(bufB, ep, 1);
      step4<0>(R, Lr, bufA, 0, a, e2);
      if (a > 4) {
        if (a > 8) loadg(bufA, ep, 2);
        step4<0>(R, Lr, bufB, 4, a, e2);
        if (a > 8) {
          if (a > 12) loadg(bufB, ep, 3);
          step4<0>(R, Lr, bufA, 8, a, e2);
          if (a > 12) step4<0>(R, Lr, bufB, 12, a, e2);
        }
      }
      float* P = wsP + ((size_t)(c - 1) * BB + b) * 49 + i * KK;
      #pragma unroll
      for (int j = 0; j < KK; j++) P[j] = Lr + flog2(R[j]);
    }
  } else {
    int b = tid - NMAT;
    int len = wlen[b];
    int a = len > 16 ? 16 : len;        // guaranteed >=16 here, but stay general
    const float* ep = em + (size_t)b * (TT * KK);
    float bufA[28], bufB[28];
    loadg(bufA, ep, 0);
    if (a > 4) loadg(bufB, ep, 1);
    float u[KK], Ls;
    {
      float a2[KK];
      #pragma unroll
      for (int j = 0; j < KK; j++) a2[j] = (stt[j] + bufA[j]) * L2E;
      float m = a2[0];
      #pragma unroll
      for (int j = 1; j < KK; j++) m = fmaxf(m, a2[j]);
      #pragma unroll
      for (int j = 0; j < KK; j++) u[j] = fexp2(a2[j] - m);
      Ls = m;
    }
    step4<1>(u, Ls, bufA, 0, a, e2);
    if (a > 4) {
      if (a > 8) loadg(bufA, ep, 2);
      step4<0>(u, Ls, bufB, 4, a, e2);
      if (a > 8) {
        if (a > 12) loadg(bufB, ep, 3);
        step4<0>(u, Ls, bufA, 8, a, e2);
        if (a > 12) step4<0>(u, Ls, bufB, 12, a, e2);
      }
    }
    #pragma unroll
    for (int j = 0; j < KK; j++) wsA[b * 8 + j] = Ls + flog2(u[j]);
  }
}

// ---------- p2: one wave per b ----------
__global__ __launch_bounds__(256) void crf_p2(
    const float* __restrict__ em, const int* __restrict__ tgs,
    const float* __restrict__ trn, const float* __restrict__ stt,
    const float* __restrict__ ent, const float* __restrict__ wsA,
    const float* __restrict__ wsP, const int* __restrict__ wlen,
    float* __restrict__ out)
{
  const float L2E = 1.44269504088896340736f;
  const float LN2 = 0.69314718055994530942f;
  __shared__ float sm[4];
  int w = threadIdx.x >> 6, lane = threadIdx.x & 63;
  int b = blockIdx.x * 4 + w;
  const int* trow = tgs + b * TT;
  const size_t eb = (size_t)b * (TT * KK);
  int len = wlen[b];

  // tag-path score, t-parallel (lane l owns t = l*8 .. l*8+7)
  int4 ta = *(const int4*)(trow + lane * 8);
  int4 tb = *(const int4*)(trow + lane * 8 + 4);
  int tga[8] = {ta.x, ta.y, ta.z, ta.w, tb.x, tb.y, tb.z, tb.w};
  int tprev = lane ? trow[lane * 8 - 1] : 0;
  float scp = 0.f;
  #pragma unroll
  for (int s = 0; s < 8; s++) {
    int t = lane * 8 + s; int tg = tga[s];
    if (t == 0)          scp += stt[tg] + em[eb + tg];
    else if (t < len)    scp += trn[tprev * KK + tg] + em[eb + (size_t)t * KK + tg];
    if (t == len - 1)    scp += ent[tg];
    tprev = tg;
  }
  float score = scp;
  #pragma unroll
  for (int o = 1; o < 64; o <<= 1) score += __shfl_xor(score, o);

  // combine chunk maps (lane j owns state j; depth-2 prefetch)
  float A = (lane < KK) ? wsA[b * 8 + lane] : -1e30f;
  int j = (lane < KK) ? lane : 0;
  int nact = (len - 1) >> 4; if (nact > 31) nact = 31;
  const float* Pb = wsP + (size_t)b * 49;
  const size_t cs = (size_t)BB * 49;
  float cur[KK];
  if (nact >= 1) {
    #pragma unroll
    for (int i = 0; i < KK; i++) cur[i] = Pb[i * KK + j];
  }
  for (int c2 = 1; c2 <= nact; c2++) {
    float nxt[KK];
    if (c2 < nact) {
      #pragma unroll
      for (int i = 0; i < KK; i++) nxt[i] = Pb[(size_t)c2 * cs + i * KK + j];
    }
    float v[KK];
    #pragma unroll
    for (int i = 0; i < KK; i++) v[i] = __shfl(A, i) + cur[i];
    float m = v[0];
    #pragma unroll
    for (int i = 1; i < KK; i++) m = fmaxf(m, v[i]);
    float ssum = 0.f;
    #pragma unroll
    for (int i = 0; i < KK; i++) ssum += fexp2(v[i] - m);
    A = m + flog2(ssum);
    #pragma unroll
    for (int i = 0; i < KK; i++) cur[i] = nxt[i];
  }

  float x = (lane < KK) ? A + ent[lane] * L2E : -1e30f;
  float mx = x;
  #pragma unroll
  for (int o = 1; o < 8; o <<= 1) mx = fmaxf(mx, __shfl_xor(mx, o));
  float se = fexp2(x - mx);
  #pragma unroll
  for (int o = 1; o < 8; o <<= 1) se += __shfl_xor(se, o);

  if (lane == 0) {
    float logz = LN2 * (mx + flog2(se));
    sm[w] = (logz - score) * (1.0f / BB);
  }
  __syncthreads();
  if (threadIdx.x == 0) atomicAdd(out, sm[0] + sm[1] + sm[2] + sm[3]);
}

extern "C" void kernel_launch(void* const* d_in, const int* in_sizes, int n_in,
                              void* d_out, int out_size, void* d_ws, size_t ws_size,
                              hipStream_t stream) {
  const float* em  = (const float*)d_in[0];
  const int*   msk = (const int*)d_in[1];
  const int*   tgs = (const int*)d_in[2];
  const float* trn = (const float*)d_in[3];
  const float* stt = (const float*)d_in[4];
  const float* ent = (const float*)d_in[5];
  float* out = (float*)d_out;

  float* wsA  = (float*)d_ws;                      // BB*8
  float* wsP  = wsA + (size_t)BB * 8;              // 31*BB*49
  float* wse2 = wsP + (size_t)31 * BB * 49;        // 64
  int*   wlen = (int*)(wse2 + 64);                 // BB

  hipMemsetAsync(out, 0, sizeof(float), stream);
  hipLaunchKernelGGL(crf_len, dim3(BB * 64 / 256), dim3(256), 0, stream,
                     msk, trn, wlen, wse2);
  hipLaunchKernelGGL(crf_p1, dim3((NMAT + BB) / 256), dim3(256), 0, stream,
                     em, wlen, wse2, stt, wsA, wsP);
  hipLaunchKernelGGL(crf_p2, dim3(BB / 4), dim3(256), 0, stream,
                     em, tgs, trn, stt, ent, wsA, wsP, wlen, out);
}